// Round 1
// baseline (378.971 us; speedup 1.0000x reference)
//
#include <hip/hip_runtime.h>
#include <math.h>

// x (8, 96, 256, 256) fp32; K=3, pad=1, stride=1.
//   pooled = mean(x, axis=(2,3)); hid = relu(pooled@w1.T+b1);
//   kw = softmax(hid@w2.T+b2)  (8,9)
//   out[b,c,i,j] = sum_{di,dj} kw[b,di*3+dj] * x_pad[b,c,i+di-1,j+dj-1]

#define NB 8
#define NC 96
#define HH 256
#define WW 256
#define PLANE (HH * WW)
#define NPLANES (NB * NC)

typedef float vfloat4 __attribute__((ext_vector_type(4)));  // clang-native, NT-store OK

// ---------------- Kernel 1: global average pool (quarter-plane partials) ----------------
// 3072 blocks = 4 per (b,c) plane; each reduces a 16384-float quarter.
// 4x the blocks of the old version (12 blocks/CU demanded -> saturates waves/CU),
// 16-deep fully-unrolled per-thread load chain instead of 64.
__global__ __launch_bounds__(256) void pool_kernel(const float* __restrict__ x,
                                                   float* __restrict__ partial) {
    const int blk = blockIdx.x;          // 0..3071
    const int tid = threadIdx.x;
    const vfloat4* xp = (const vfloat4*)x + (size_t)(blk >> 2) * (PLANE / 4)
                        + (size_t)(blk & 3) * 4096;
    float s = 0.f;
#pragma unroll
    for (int k = 0; k < 16; ++k) {
        vfloat4 v = xp[k * 256 + tid];
        s += (v.x + v.y) + (v.z + v.w);
    }
#pragma unroll
    for (int off = 32; off > 0; off >>= 1) s += __shfl_down(s, off);
    __shared__ float ws[4];
    if ((tid & 63) == 0) ws[tid >> 6] = s;
    __syncthreads();
    if (tid == 0) partial[blk] = (ws[0] + ws[1]) + (ws[2] + ws[3]);
}

// ---------------- Kernel 2: partial-reduce + tiny attention MLP + softmax ----------------
__global__ __launch_bounds__(128) void attn_kernel(const float* __restrict__ partial,
                                                   const float* __restrict__ w1,
                                                   const float* __restrict__ b1,
                                                   const float* __restrict__ w2,
                                                   const float* __restrict__ b2,
                                                   float* __restrict__ kw) {
    const int b = blockIdx.x;
    const int tid = threadIdx.x;
    __shared__ float p[NC];
    __shared__ float hid[12];
    __shared__ float logit[9];
    if (tid < NC) {
        const float* pp = partial + ((size_t)(b * NC + tid) << 2);
        p[tid] = ((pp[0] + pp[1]) + (pp[2] + pp[3])) * (1.0f / (float)PLANE);
    }
    __syncthreads();
    if (tid < 12) {
        float a = b1[tid];
#pragma unroll
        for (int c = 0; c < NC; ++c) a = fmaf(p[c], w1[tid * NC + c], a);
        hid[tid] = a > 0.f ? a : 0.f;
    }
    __syncthreads();
    if (tid < 9) {
        float a = b2[tid];
#pragma unroll
        for (int j = 0; j < 12; ++j) a = fmaf(hid[j], w2[tid * 12 + j], a);
        logit[tid] = a;
    }
    __syncthreads();
    if (tid == 0) {
        float m = logit[0];
#pragma unroll
        for (int q = 1; q < 9; ++q) m = fmaxf(m, logit[q]);
        float e[9], s = 0.f;
#pragma unroll
        for (int q = 0; q < 9; ++q) { e[q] = __expf(logit[q] - m); s += e[q]; }
        float inv = 1.f / s;
#pragma unroll
        for (int q = 0; q < 9; ++q) kw[b * 9 + q] = e[q] * inv;
    }
}

// ---------------- Kernel 3: rolling-row dynamic 3x3 depthwise conv ----------------
// One wave (64 lanes) owns a full 256-float row (lane = float4 column), walks a
// 16-row strip keeping 3 rows live. Horizontal halos via shuffles; the raw global
// load for the next row is issued one iteration ahead (prefetch register) so the
// vmcnt wait + ds_bpermute pair are off the load critical path.
struct Row {
    vfloat4 v;
    float hl, hr;  // col jc-1 (from lane-1) and col jc+4 (from lane+1)
};

__device__ __forceinline__ vfloat4 raw_row(const float* __restrict__ xpl, int r,
                                           int lane) {
    if ((unsigned)r < (unsigned)HH)
        return *(const vfloat4*)(xpl + (size_t)r * WW + (lane << 2));
    return (vfloat4){0.f, 0.f, 0.f, 0.f};  // zero pad rows -1 / 256 (wave-uniform r)
}

__device__ __forceinline__ Row make_row(vfloat4 v, int lane) {
    Row r;
    r.v = v;
    float up = __shfl_up(v.w, 1);
    float dn = __shfl_down(v.x, 1);
    r.hl = (lane == 0) ? 0.f : up;   // zero pad at j = -1
    r.hr = (lane == 63) ? 0.f : dn;  // zero pad at j = 256
    return r;
}

__device__ __forceinline__ void row_fma(const Row& r, float wl, float wc, float wr,
                                        vfloat4& o) {
    o.x = fmaf(wl, r.hl,  fmaf(wc, r.v.x, fmaf(wr, r.v.y, o.x)));
    o.y = fmaf(wl, r.v.x, fmaf(wc, r.v.y, fmaf(wr, r.v.z, o.y)));
    o.z = fmaf(wl, r.v.y, fmaf(wc, r.v.z, fmaf(wr, r.v.w, o.z)));
    o.w = fmaf(wl, r.v.z, fmaf(wc, r.v.w, fmaf(wr, r.hr,  o.w)));
}

// grid: (4 strips-of-4-waves, 96 channels, 8 batches); block 256 = 4 waves,
// each wave a 16-row strip. Per wave: 18 rows loaded / 16 produced (1.125x).
// 3072 blocks -> 32 waves/CU demanded (was 24 at 32-row strips).
__global__ __launch_bounds__(256) void conv_kernel(const float* __restrict__ x,
                                                   const float* __restrict__ kw9,
                                                   float* __restrict__ out) {
    const int lane = threadIdx.x & 63;
    const int strip = (blockIdx.x << 2) + (threadIdx.x >> 6);  // 0..15
    const int rs = strip << 4;                                 // first output row

    const size_t base = ((size_t)(blockIdx.z * NC + blockIdx.y)) * PLANE;
    const float* xpl = x + base;
    float* opl = out + base;

    float w[9];
#pragma unroll
    for (int p = 0; p < 9; ++p) w[p] = kw9[blockIdx.z * 9 + p];  // block-uniform

    Row a = make_row(raw_row(xpl, rs - 1, lane), lane);
    Row b = make_row(raw_row(xpl, rs, lane), lane);
    vfloat4 pre = raw_row(xpl, rs + 1, lane);  // row rs+1, shuffles deferred

#pragma unroll 4
    for (int i = rs; i < rs + 16; ++i) {
        // issue next raw load first (independent address) -> a full iteration of
        // FMAs + store sits between the load and its vmcnt wait next iteration
        vfloat4 nxt = (i + 2 <= rs + 16) ? raw_row(xpl, i + 2, lane)
                                         : (vfloat4){0.f, 0.f, 0.f, 0.f};
        Row c = make_row(pre, lane);
        vfloat4 o = (vfloat4){0.f, 0.f, 0.f, 0.f};
        row_fma(a, w[0], w[1], w[2], o);
        row_fma(b, w[3], w[4], w[5], o);
        row_fma(c, w[6], w[7], w[8], o);
        __builtin_nontemporal_store(o, (vfloat4*)(opl + (size_t)i * WW + (lane << 2)));
        a = b; b = c; pre = nxt;
    }
}

extern "C" void kernel_launch(void* const* d_in, const int* in_sizes, int n_in,
                              void* d_out, int out_size, void* d_ws, size_t ws_size,
                              hipStream_t stream) {
    const float* x  = (const float*)d_in[0];
    const float* w1 = (const float*)d_in[1];
    const float* b1 = (const float*)d_in[2];
    const float* w2 = (const float*)d_in[3];
    const float* b2 = (const float*)d_in[4];
    float* out = (float*)d_out;

    float* partial = (float*)d_ws;        // 3072 floats (4 per plane)
    float* kw      = partial + NPLANES * 4;  // 72 floats

    pool_kernel<<<NPLANES * 4, 256, 0, stream>>>(x, partial);
    attn_kernel<<<NB, 128, 0, stream>>>(partial, w1, b1, w2, b2, kw);
    dim3 grid(4, NC, NB);                 // 3072 blocks, 12/CU demanded, 32 waves/CU
    conv_kernel<<<grid, 256, 0, stream>>>(x, kw, out);
}